// Round 1
// baseline (608.208 us; speedup 1.0000x reference)
//
#include <hip/hip_runtime.h>

#define B 64
#define N 1024
#define E 16384
#define WPR 32          // words per adjacency row = N/32
#define NITER 5

// ---- workspace layout (bytes) ----
#define ADJ_OFF   0
#define ADJ_BYTES ((size_t)B * N * WPR * 4)          // 8 MiB bit adjacency
#define DEG_OFF   (ADJ_OFF + ADJ_BYTES)
#define DEG_BYTES ((size_t)B * N * 4)
#define K_OFF     (DEG_OFF + DEG_BYTES)
#define K_BYTES   ((size_t)B * 4)
#define LAB_OFF   (K_OFF + 256)                      // pad for alignment
#define LAB_BYTES ((size_t)B * N * 4)
#define HASH_OFF  (LAB_OFF + LAB_BYTES)
#define HASH_BYTES ((size_t)B * N * 4)
#define FEATS_OFF (HASH_OFF + HASH_BYTES)
#define FEATS_BYTES ((size_t)B * N * 4)
#define GRAM_OFF  (FEATS_OFF + FEATS_BYTES)
#define GRAM_BYTES ((size_t)B * B * 4)
#define WS_TOTAL  (GRAM_OFF + GRAM_BYTES)            // ~9.03 MiB

// Build bit adjacency: mask[b, src, dst] = 1. atomicOr is idempotent, so
// duplicate edges collapse exactly like the reference's .set(True).
__global__ void build_adj_k(const int* __restrict__ src, const int* __restrict__ dst,
                            unsigned int* __restrict__ adj) {
    int idx = blockIdx.x * blockDim.x + threadIdx.x;
    if (idx >= B * E) return;
    int b = idx >> 14;                    // / E
    int s = src[idx];
    int d = dst[idx];
    atomicOr(&adj[((size_t)(b * N + s)) * WPR + (d >> 5)], 1u << (d & 31));
}

// deg[b,i] = popcount(row); K[b] = max_i deg  (iteration-invariant)
__global__ void deg_k(const unsigned int* __restrict__ adj, int* __restrict__ deg,
                      int* __restrict__ Kmax) {
    int idx = blockIdx.x * blockDim.x + threadIdx.x;   // b*N + i
    if (idx >= B * N) return;
    const uint4* row = (const uint4*)(adj + (size_t)idx * WPR);
    int d = 0;
#pragma unroll
    for (int w = 0; w < WPR / 4; ++w) {
        uint4 v = row[w];
        d += __popc(v.x) + __popc(v.y) + __popc(v.z) + __popc(v.w);
    }
    deg[idx] = d;
    atomicMax(&Kmax[idx >> 10], d);
}

// labels_cur = initial labels; bincount initial labels into feats
__global__ void init_k(const int* __restrict__ lab_in, int* __restrict__ lab,
                       unsigned int* __restrict__ feats) {
    int idx = blockIdx.x * blockDim.x + threadIdx.x;
    if (idx >= B * N) return;
    int l = lab_in[idx];
    lab[idx] = l;
    int b = idx >> 10;
    atomicAdd(&feats[(size_t)b * N + l], 1u);
}

// seg[b,i] = sum of labels over set bits; hashed = (K*w0)*lab + w1*((seg+deg)-K)
// computed with _rn intrinsics to forbid FMA contraction -> bitwise match vs numpy.
__global__ void seg_hash_k(const unsigned int* __restrict__ adj, const int* __restrict__ lab,
                           const int* __restrict__ deg, const int* __restrict__ Kmax,
                           const float* __restrict__ hw, float* __restrict__ hashed) {
    int idx = blockIdx.x * blockDim.x + threadIdx.x;   // b*N + i
    if (idx >= B * N) return;
    int b = idx >> 10;
    const unsigned int* row = adj + (size_t)idx * WPR;
    const int* labg = lab + (size_t)b * N;
    int s = 0;
#pragma unroll 4
    for (int w = 0; w < WPR; ++w) {
        unsigned int word = row[w];
        int base = w << 5;
        while (word) {
            int j = __ffs(word) - 1;
            word &= word - 1;
            s += labg[base + j];
        }
    }
    float Kf   = (float)Kmax[b];
    float labf = (float)lab[idx];
    float degf = (float)deg[idx];
    float segf = (float)s;           // exact: |seg| < 2^24
    float w0 = hw[0], w1 = hw[1];
    float t1 = __fmul_rn(__fmul_rn(Kf, w0), labf);
    float t2 = __fmul_rn(w1, __fsub_rn(__fadd_rn(segf, degf), Kf));
    hashed[idx] = __fadd_rn(t1, t2);
}

// Per-graph unique-inverse (dense rank of sorted distinct hash values),
// scatter new labels, and bincount them into feats. One block per graph.
__global__ void __launch_bounds__(1024) rank_k(const float* __restrict__ hashed,
                                               int* __restrict__ lab,
                                               unsigned int* __restrict__ feats) {
    __shared__ float s_key[N];
    __shared__ int   s_idx[N];
    __shared__ int   s_scan[N];
    int b = blockIdx.x;
    int t = threadIdx.x;
    s_key[t] = hashed[(size_t)b * N + t];
    s_idx[t] = t;
    __syncthreads();
    // bitonic sort ascending (ties unordered — rank is equality-based, so fine)
    for (int k = 2; k <= N; k <<= 1) {
        for (int j = k >> 1; j > 0; j >>= 1) {
            int ixj = t ^ j;
            if (ixj > t) {
                bool up = ((t & k) == 0);
                float a = s_key[t], c = s_key[ixj];
                if ((a > c) == up) {
                    s_key[t] = c; s_key[ixj] = a;
                    int tmp = s_idx[t]; s_idx[t] = s_idx[ixj]; s_idx[ixj] = tmp;
                }
            }
            __syncthreads();
        }
    }
    // boundary flags + inclusive Hillis-Steele scan -> dense rank in sorted order
    int f = (t > 0 && s_key[t] != s_key[t - 1]) ? 1 : 0;
    s_scan[t] = f;
    __syncthreads();
    for (int off = 1; off < N; off <<= 1) {
        int v = (t >= off) ? s_scan[t - off] : 0;
        __syncthreads();
        s_scan[t] += v;
        __syncthreads();
    }
    int rank = s_scan[t];
    lab[(size_t)b * N + s_idx[t]] = rank;
    atomicAdd(&feats[(size_t)b * N + rank], 1u);
}

// gram[i,j] = dot(feats[i], feats[j]) — exact in int32 (max ~3.8e7)
__global__ void gram_k(const unsigned int* __restrict__ feats, float* __restrict__ gram) {
    int i = blockIdx.x, j = blockIdx.y;
    int lane = threadIdx.x;               // 64 lanes = one wave
    const unsigned int* fi = feats + (size_t)i * N;
    const unsigned int* fj = feats + (size_t)j * N;
    int s = 0;
    for (int l = lane; l < N; l += 64) s += (int)(fi[l] * fj[l]);
#pragma unroll
    for (int off = 32; off > 0; off >>= 1) s += __shfl_down(s, off);
    if (lane == 0) gram[i * B + j] = (float)s;
}

__global__ void norm_k(const float* __restrict__ gram, float* __restrict__ out) {
    int idx = blockIdx.x * blockDim.x + threadIdx.x;
    if (idx >= B * B) return;
    int i = idx >> 6, j = idx & 63;
    out[idx] = gram[idx] / sqrtf(gram[i * B + i] * gram[j * B + j]);
}

extern "C" void kernel_launch(void* const* d_in, const int* in_sizes, int n_in,
                              void* d_out, int out_size, void* d_ws, size_t ws_size,
                              hipStream_t stream) {
    const int*   esrc = (const int*)d_in[0];
    const int*   edst = (const int*)d_in[1];
    const int*   lab0 = (const int*)d_in[2];
    const float* hw   = (const float*)d_in[3];

    char* ws = (char*)d_ws;
    unsigned int* adj   = (unsigned int*)(ws + ADJ_OFF);
    int*          deg   = (int*)(ws + DEG_OFF);
    int*          Kmax  = (int*)(ws + K_OFF);
    int*          lab   = (int*)(ws + LAB_OFF);
    float*        hashed= (float*)(ws + HASH_OFF);
    unsigned int* feats = (unsigned int*)(ws + FEATS_OFF);
    float*        gram  = (float*)(ws + GRAM_OFF);

    // zero adj + Kmax + feats (deg/lab/hashed/gram are fully overwritten)
    hipMemsetAsync(d_ws, 0, WS_TOTAL, stream);

    build_adj_k<<<(B * E + 255) / 256, 256, 0, stream>>>(esrc, edst, adj);
    deg_k<<<(B * N + 255) / 256, 256, 0, stream>>>(adj, deg, Kmax);
    init_k<<<(B * N + 255) / 256, 256, 0, stream>>>(lab0, lab, feats);

    for (int it = 0; it < NITER; ++it) {
        seg_hash_k<<<(B * N + 255) / 256, 256, 0, stream>>>(adj, lab, deg, Kmax, hw, hashed);
        rank_k<<<B, 1024, 0, stream>>>(hashed, lab, feats);
    }

    gram_k<<<dim3(B, B), 64, 0, stream>>>(feats, gram);
    norm_k<<<(B * B + 255) / 256, 256, 0, stream>>>(gram, (float*)d_out);
}

// Round 2
// 272.360 us; speedup vs baseline: 2.2331x; 2.2331x over previous
//
#include <hip/hip_runtime.h>

#define B 64
#define N 1024
#define E 16384
#define WPR 32          // words per adjacency row = N/32
#define NITER 5

// ---- workspace layout (bytes) ----
// [ adj 8MiB | Kmax 256B | feats 256KiB ]  <- zeroed by one memset
// [ lab 256KiB | gram 16KiB ]              <- fully overwritten, no zeroing
#define ADJ_OFF   0
#define ADJ_BYTES ((size_t)B * N * WPR * 4)
#define K_OFF     (ADJ_OFF + ADJ_BYTES)
#define K_BYTES   ((size_t)256)
#define FEATS_OFF (K_OFF + K_BYTES)
#define FEATS_BYTES ((size_t)B * N * 4)
#define ZERO_BYTES (FEATS_OFF + FEATS_BYTES)
#define LAB_OFF   (ZERO_BYTES)
#define LAB_BYTES ((size_t)B * N * 4)
#define GRAM_OFF  (LAB_OFF + LAB_BYTES)
#define GRAM_BYTES ((size_t)B * B * 4)

// Build bit adjacency: mask[b, src, dst] = 1. atomicOr is idempotent, so
// duplicate edges collapse exactly like the reference's .set(True).
__global__ void build_adj_k(const int* __restrict__ src, const int* __restrict__ dst,
                            unsigned int* __restrict__ adj) {
    int idx = blockIdx.x * blockDim.x + threadIdx.x;
    if (idx >= B * E) return;
    int b = idx >> 14;                    // / E
    int s = src[idx];
    int d = dst[idx];
    atomicOr(&adj[((size_t)(b * N + s)) * WPR + (d >> 5)], 1u << (d & 31));
}

// Kmax[b] = max_i popcount(row(b,i)).  Block-level reduction -> 1 atomic/block
// (4 atomics per graph instead of 1024: R1's 310us was same-address atomicMax
// serialization at ~300ns each).
__global__ void kmax_k(const unsigned int* __restrict__ adj, int* __restrict__ Kmax) {
    __shared__ int red[256];
    int t = threadIdx.x;
    int idx = blockIdx.x * 256 + t;                 // b*N + i; block lies in one graph
    const uint4* row = (const uint4*)(adj + (size_t)idx * WPR);
    int d = 0;
#pragma unroll
    for (int w = 0; w < WPR / 4; ++w) {
        uint4 v = row[w];
        d += __popc(v.x) + __popc(v.y) + __popc(v.z) + __popc(v.w);
    }
    red[t] = d;
    __syncthreads();
#pragma unroll
    for (int off = 128; off > 0; off >>= 1) {
        if (t < off) red[t] = max(red[t], red[t + off]);
        __syncthreads();
    }
    if (t == 0) atomicMax(&Kmax[blockIdx.x >> 2], red[0]);
}

// labels_cur = initial labels; bincount (labels < 16) via LDS aggregation.
__global__ void init_k(const int* __restrict__ lab_in, int* __restrict__ lab,
                       unsigned int* __restrict__ feats) {
    __shared__ unsigned int cnt[16];
    int t = threadIdx.x;
    if (t < 16) cnt[t] = 0;
    __syncthreads();
    int idx = blockIdx.x * 256 + t;                 // block lies in one graph
    int l = lab_in[idx];
    lab[idx] = l;
    atomicAdd(&cnt[l], 1u);
    __syncthreads();
    if (t < 16) atomicAdd(&feats[(size_t)(blockIdx.x >> 2) * N + t], cnt[t]);
}

// One fused WL iteration for one graph per block:
//   seg/deg from the bit-adjacency row (labels staged in LDS),
//   hash with exact _rn op order (bitwise match vs numpy),
//   bitonic sort + boundary scan -> dense ranks (unique-inverse),
//   scatter new labels, bincount ranks (LDS atomics, then plain global add:
//   bin [b*N+r] is touched only by block b within this launch).
__global__ void __launch_bounds__(1024) wl_iter_k(const unsigned int* __restrict__ adj,
                                                  const int* __restrict__ Kmax,
                                                  const float* __restrict__ hw,
                                                  int* __restrict__ lab,
                                                  unsigned int* __restrict__ feats) {
    __shared__ float s_key[N];
    __shared__ int   s_idx[N];
    __shared__ int   s_scan[N];
    __shared__ int   s_lab[N];          // labels, later reused as rank counts
    int b = blockIdx.x;
    int t = threadIdx.x;
    s_lab[t] = lab[(size_t)b * N + t];
    __syncthreads();

    // deg + seg from this node's adjacency row
    const unsigned int* row = adj + ((size_t)b * N + t) * WPR;
    int s = 0, d = 0;
#pragma unroll 4
    for (int w = 0; w < WPR; ++w) {
        unsigned int word = row[w];
        d += __popc(word);
        int base = w << 5;
        while (word) {
            int j = __ffs(word) - 1;
            word &= word - 1;
            s += s_lab[base + j];
        }
    }
    float Kf   = (float)Kmax[b];
    float labf = (float)s_lab[t];
    float degf = (float)d;
    float segf = (float)s;              // exact: |seg| < 2^24
    float w0 = hw[0], w1 = hw[1];
    float t1 = __fmul_rn(__fmul_rn(Kf, w0), labf);
    float t2 = __fmul_rn(w1, __fsub_rn(__fadd_rn(segf, degf), Kf));
    s_key[t] = __fadd_rn(t1, t2);
    s_idx[t] = t;
    __syncthreads();

    // bitonic sort ascending (ties unordered — rank is equality-based)
    for (int k = 2; k <= N; k <<= 1) {
        for (int j = k >> 1; j > 0; j >>= 1) {
            int ixj = t ^ j;
            if (ixj > t) {
                bool up = ((t & k) == 0);
                float a = s_key[t], c = s_key[ixj];
                if ((a > c) == up) {
                    s_key[t] = c; s_key[ixj] = a;
                    int tmp = s_idx[t]; s_idx[t] = s_idx[ixj]; s_idx[ixj] = tmp;
                }
            }
            __syncthreads();
        }
    }

    // boundary flags + inclusive Hillis-Steele scan -> dense rank
    int f = (t > 0 && s_key[t] != s_key[t - 1]) ? 1 : 0;
    s_scan[t] = f;
    __syncthreads();
    for (int off = 1; off < N; off <<= 1) {
        int v = (t >= off) ? s_scan[t - off] : 0;
        __syncthreads();
        s_scan[t] += v;
        __syncthreads();
    }
    int rank = s_scan[t];
    lab[(size_t)b * N + s_idx[t]] = rank;

    // bincount ranks: LDS aggregate, then plain global read-modify-write
    s_lab[t] = 0;
    __syncthreads();
    atomicAdd((unsigned int*)&s_lab[rank], 1u);
    __syncthreads();
    unsigned int c = (unsigned int)s_lab[t];
    if (c) feats[(size_t)b * N + t] += c;
}

// gram[i,j] = dot(feats[i], feats[j]) — exact in int32 (max ~3.8e7)
__global__ void gram_k(const unsigned int* __restrict__ feats, float* __restrict__ gram) {
    int i = blockIdx.x, j = blockIdx.y;
    int lane = threadIdx.x;               // 64 lanes = one wave
    const unsigned int* fi = feats + (size_t)i * N;
    const unsigned int* fj = feats + (size_t)j * N;
    int s = 0;
    for (int l = lane; l < N; l += 64) s += (int)(fi[l] * fj[l]);
#pragma unroll
    for (int off = 32; off > 0; off >>= 1) s += __shfl_down(s, off);
    if (lane == 0) gram[i * B + j] = (float)s;
}

__global__ void norm_k(const float* __restrict__ gram, float* __restrict__ out) {
    int idx = blockIdx.x * blockDim.x + threadIdx.x;
    if (idx >= B * B) return;
    int i = idx >> 6, j = idx & 63;
    out[idx] = gram[idx] / sqrtf(gram[i * B + i] * gram[j * B + j]);
}

extern "C" void kernel_launch(void* const* d_in, const int* in_sizes, int n_in,
                              void* d_out, int out_size, void* d_ws, size_t ws_size,
                              hipStream_t stream) {
    const int*   esrc = (const int*)d_in[0];
    const int*   edst = (const int*)d_in[1];
    const int*   lab0 = (const int*)d_in[2];
    const float* hw   = (const float*)d_in[3];

    char* ws = (char*)d_ws;
    unsigned int* adj   = (unsigned int*)(ws + ADJ_OFF);
    int*          Kmax  = (int*)(ws + K_OFF);
    unsigned int* feats = (unsigned int*)(ws + FEATS_OFF);
    int*          lab   = (int*)(ws + LAB_OFF);
    float*        gram  = (float*)(ws + GRAM_OFF);

    hipMemsetAsync(d_ws, 0, ZERO_BYTES, stream);    // adj + Kmax + feats

    build_adj_k<<<(B * E + 255) / 256, 256, 0, stream>>>(esrc, edst, adj);
    kmax_k<<<B * N / 256, 256, 0, stream>>>(adj, Kmax);
    init_k<<<B * N / 256, 256, 0, stream>>>(lab0, lab, feats);

    for (int it = 0; it < NITER; ++it)
        wl_iter_k<<<B, 1024, 0, stream>>>(adj, Kmax, hw, lab, feats);

    gram_k<<<dim3(B, B), 64, 0, stream>>>(feats, gram);
    norm_k<<<(B * B + 255) / 256, 256, 0, stream>>>(gram, (float*)d_out);
}